// Round 15
// baseline (228.599 us; speedup 1.0000x reference)
//
#include <hip/hip_runtime.h>

#define BB 4
#define HH 1024
#define WW 1024
#define K2 9
#define PAD 1

#define R   12            // halo radius (covers ~6 sigma offsets)
#define TW  64            // tile width
#define TH  8             // tile height (2 rows per thread: ty and ty+4)
#define RW  (TW + 2*R)    // 88
#define RH  (TH + 2*R)    // 32
#define RSZ (RW * RH)     // 2816 floats = 11264 B

// launch_bounds: 5 waves/EU min -> VGPR cap ~102; enough for 54-float payload,
// stays above the ~15 measured waves/CU plateau (R1/R2/R5/R7 all ~15 @ VGPR<=64).
__global__ __launch_bounds__(256, 5) void dcn_kernel(
    const float* __restrict__ init_dem,   // [B,1,H,W]
    const float* __restrict__ weight,     // [B,K2,H,W]
    const float* __restrict__ offset,     // [B,2*K2,H,W]
    const float* __restrict__ wk,         // [K2]
    const float* __restrict__ bias,       // [1]
    float* __restrict__ out)              // [B,1,H,W]
{
    __shared__ float region[RSZ];

    const int HW = HH * WW;

    // batch pinned to an XCD pair (blockIdx % 8 -> XCD heuristic)
    int i    = blockIdx.x;
    int b    = (i & 7) >> 1;
    int widx = ((i >> 3) << 1) | (i & 1);     // 0 .. 2047, bijective
    int tile_w = widx & 15;                   // W/TW = 16
    int tile_h = widx >> 4;                   // H/TH = 128
    int w0 = tile_w * TW;
    int h0 = tile_h * TH;

    const float* img = init_dem + (size_t)b * HW;

    const int tid = threadIdx.x;
    const int tx  = tid & 63;
    const int ty  = tid >> 6;

    const int rem0 = (h0 + ty) * WW + w0 + tx;
    const int rem1 = rem0 + 4 * WW;

    const float* wq = weight + (size_t)b * K2 * HW;
    const float* oq = offset + (size_t)b * 2 * K2 * HW;

    // ---- ONE latency event: all 54 scalar-NT stream loads issued up front ----
    // px0's 27 first (its compute can start at vmcnt<=27), then px1's 27.
    float wt0[K2], dy0[K2], dx0[K2];
#pragma unroll
    for (int k = 0; k < K2; ++k) {
        wt0[k] = __builtin_nontemporal_load(wq + (size_t)k * HW + rem0);
        dy0[k] = __builtin_nontemporal_load(oq + (size_t)(2 * k) * HW + rem0);
        dx0[k] = __builtin_nontemporal_load(oq + (size_t)(2 * k + 1) * HW + rem0);
    }
    float wt1[K2], dy1[K2], dx1[K2];
#pragma unroll
    for (int k = 0; k < K2; ++k) {
        wt1[k] = __builtin_nontemporal_load(wq + (size_t)k * HW + rem1);
        dy1[k] = __builtin_nontemporal_load(oq + (size_t)(2 * k) * HW + rem1);
        dx1[k] = __builtin_nontemporal_load(oq + (size_t)(2 * k + 1) * HW + rem1);
    }

    // ---- region staging: the latency-hiding window (coalesced, L2-hit) ----
#pragma unroll
    for (int it = 0; it < RSZ / 256; ++it) {
        int e = tid + it * 256;
        int r = e / RW;
        int c = e - r * RW;
        int gy = h0 - R + r;
        int gx = w0 - R + c;
        float v = 0.f;
        if ((unsigned)gy < (unsigned)HH && (unsigned)gx < (unsigned)WW)
            v = img[gy * WW + gx];
        region[e] = v;
    }
    __syncthreads();   // drains lgkm + vmcnt: streams and region all ready

    const float bval = bias[0];
    const float fx = (float)(tx + R - PAD);

#pragma unroll
    for (int p = 0; p < 2; ++p) {
        const float* wt = p ? wt1 : wt0;
        const float* dy = p ? dy1 : dy0;
        const float* dx = p ? dx1 : dx0;
        const int   rem = p ? rem1 : rem0;
        const float fy  = (float)(ty + p * 4 + R - PAD);

        float wsum = 0.f;
#pragma unroll
        for (int k = 0; k < K2; ++k) wsum += wt[k];
        const float mean = wsum * (1.0f / K2);

        float acc = 0.f;
#pragma unroll
        for (int k = 0; k < K2; ++k) {
            const int ky = k / 3, kx = k % 3;

            float ysl = (fy + (float)ky) + dy[k];
            float xsl = (fx + (float)kx) + dx[k];

            float y0f = floorf(ysl);
            float x0f = floorf(xsl);
            float wy1 = ysl - y0f;
            float wx1 = xsl - x0f;
            float wy0 = 1.f - wy1;
            float wx0 = 1.f - wx1;

            int y0l = (int)y0f;
            int x0l = (int)x0f;

            float v00, v01, v10, v11;
            if (((unsigned)y0l < (unsigned)(RH - 1)) &
                ((unsigned)x0l < (unsigned)(RW - 1))) {
                int base = y0l * RW + x0l;
                v00 = region[base];
                v10 = region[base + RW];
                v01 = region[base + 1];
                v11 = region[base + RW + 1];
            } else {
                int y0g = y0l + (h0 - R);
                int x0g = x0l + (w0 - R);
                int y1g = y0g + 1;
                int x1g = x0g + 1;
                bool y0v = (y0g >= 0) & (y0g < HH);
                bool y1v = (y1g >= 0) & (y1g < HH);
                bool x0v = (x0g >= 0) & (x0g < WW);
                bool x1v = (x1g >= 0) & (x1g < WW);
                int yc0 = min(max(y0g, 0), HH - 1);
                int yc1 = min(max(y1g, 0), HH - 1);
                int xc0 = min(max(x0g, 0), WW - 1);
                int xc1 = min(max(x1g, 0), WW - 1);
                v00 = (y0v & x0v) ? img[(size_t)yc0 * WW + xc0] : 0.f;
                v01 = (y0v & x1v) ? img[(size_t)yc0 * WW + xc1] : 0.f;
                v10 = (y1v & x0v) ? img[(size_t)yc1 * WW + xc0] : 0.f;
                v11 = (y1v & x1v) ? img[(size_t)yc1 * WW + xc1] : 0.f;
            }

            float samp = wy0 * (wx0 * v00 + wx1 * v01)
                       + wy1 * (wx0 * v10 + wx1 * v11);
            acc += samp * (wt[k] - mean) * wk[k];
        }

        float resid = region[(ty + p * 4 + R) * RW + (tx + R)];
        float rres  = acc + bval + resid;
        __builtin_nontemporal_store(rres, out + (size_t)b * HW + rem);
    }
}

extern "C" void kernel_launch(void* const* d_in, const int* in_sizes, int n_in,
                              void* d_out, int out_size, void* d_ws, size_t ws_size,
                              hipStream_t stream) {
    const float* init_dem = (const float*)d_in[0];
    const float* weight   = (const float*)d_in[1];
    const float* offset   = (const float*)d_in[2];
    const float* wk       = (const float*)d_in[3];
    const float* bias     = (const float*)d_in[4];
    float* out            = (float*)d_out;

    const int nblocks = BB * (WW / TW) * (HH / TH);   // 4*16*128 = 8192
    dcn_kernel<<<dim3(nblocks), dim3(256), 0, stream>>>(init_dem, weight, offset, wk, bias, out);
}